// Round 2
// baseline (109.920 us; speedup 1.0000x reference)
//
#include <hip/hip_runtime.h>
#include <math.h>

#define BQ 128
#define NQ 256
#define SMAX 300
#define CCLS 5
#define CCHG 3
#define TSTR 268          // s_tab row stride (floats), cc-major [15][268]
#define RSTR 12           // s_rows row stride (floats)
#define INFV 3.0e38f

#define NBLK 256          // 2 blocks per batch (row-halves), balanced pair+ss

// ws layout (floats); total ~574 KB of the poisoned workspace, write-before-read
#define W_COL 0           // [256][256] col-min partials per row-half
#define W_SC  65536       // [256]      row-min-sum partial (per row-half)
#define W_SS  65792       // [256][304] ss column-sum partials per row-half
#define W_B   143616      // [128]      per-batch totals

// pair-block LDS (floats)
#define P_TAB   0         // 15*268 NLL table (cc-major)
#define P_COLS  4020      // 256*8 pflow pos/mom/en
#define P_ROWS  6068      // 128*12 particle rows of this half
#define P_RED   7604      // [16][128] row-min partials over ty
#define P_PART  9652      // [2]
#define SMEM_FLOATS 9656

__device__ __forceinline__ float fast_sqrtf(float x) {
    return __builtin_amdgcn_sqrtf(x);
}

__global__ __launch_bounds__(512, 2) void main_kernel(
    const int* __restrict__ p_class, const int* __restrict__ p_charge,
    const float* __restrict__ cls_logits, const float* __restrict__ chg_logits,
    const float* __restrict__ p_pos, const float* __restrict__ pf_pos,
    const float* __restrict__ p_mom, const float* __restrict__ pf_mom,
    const float* __restrict__ p_en, const float* __restrict__ pf_en,
    const float* __restrict__ setsizes, float* __restrict__ ws)
{
    __shared__ float smem[SMEM_FLOATS];
    const int t   = threadIdx.x;
    const int blk = blockIdx.x;
    const int b   = blk >> 1;         // batch
    const int h   = blk & 1;          // row-half
    const int base = b * NQ;

    float* s_tab  = smem + P_TAB;
    float* s_cols = smem + P_COLS;
    float* s_rows = smem + P_ROWS;
    float* s_red  = smem + P_RED;
    float* s_part = smem + P_PART;

    if (t < NQ) {
        // NLL table column t (pflow logits) + pflow col data
        const int gj = base + t;
        const float* cl = cls_logits + (size_t)gj * CCLS;
        float l0=cl[0], l1=cl[1], l2=cl[2], l3=cl[3], l4=cl[4];
        float mx = fmaxf(fmaxf(fmaxf(l0,l1),fmaxf(l2,l3)),l4);
        float lse = mx + __logf(__expf(l0-mx)+__expf(l1-mx)+__expf(l2-mx)+
                                __expf(l3-mx)+__expf(l4-mx));
        const float* gl = chg_logits + (size_t)gj * CCHG;
        float g0=gl[0], g1=gl[1], g2=gl[2];
        float gmx = fmaxf(fmaxf(g0,g1),g2);
        float glse = gmx + __logf(__expf(g0-gmx)+__expf(g1-gmx)+__expf(g2-gmx));
        float nc[CCLS] = {lse-l0, lse-l1, lse-l2, lse-l3, lse-l4};
        float ng[CCHG] = {glse-g0, glse-g1, glse-g2};
        #pragma unroll
        for (int c = 0; c < CCLS; ++c)
            #pragma unroll
            for (int g = 0; g < CCHG; ++g)
                s_tab[(c*CCHG+g)*TSTR + t] = nc[c] + ng[g];

        float* cr = &s_cols[t*8];
        cr[0]=pf_pos[gj*3+0]; cr[1]=pf_pos[gj*3+1]; cr[2]=pf_pos[gj*3+2];
        cr[3]=pf_mom[gj*3+0]; cr[4]=pf_mom[gj*3+1]; cr[5]=pf_mom[gj*3+2];
        cr[6]=pf_en[gj];      cr[7]=0.0f;
    } else if (t < NQ + 128) {
        // particle row rr of this half
        const int rr = t - NQ;
        const int gr = base + h*128 + rr;
        float* rw = &s_rows[rr*RSTR];
        rw[0]=p_pos[gr*3+0]; rw[1]=p_pos[gr*3+1]; rw[2]=p_pos[gr*3+2];
        rw[3]=p_mom[gr*3+0]; rw[4]=p_mom[gr*3+1]; rw[5]=p_mom[gr*3+2];
        rw[6]=p_en[gr];
        rw[7]=__int_as_float(p_class[gr]*CCHG + p_charge[gr]);
    }
    __syncthreads();

    const int tx = t & 31;    // local rows tx + 32r, r<4 (128 rows of this half)
    const int ty = t >> 5;    // cols ty*16 + c
    const int c0 = ty * 16;

    float4 ra[4], rb[4];
    int ccr[4];
    #pragma unroll
    for (int r = 0; r < 4; ++r) {
        const int row = tx + 32*r;
        ra[r] = *(const float4*)&s_rows[row*RSTR];
        rb[r] = *(const float4*)&s_rows[row*RSTR + 4];
        ccr[r] = __float_as_int(rb[r].w) * TSTR;
    }
    float rmin[4] = {INFV, INFV, INFV, INFV};

    // ss streaming state: this half's 128 rows, col = t (t < 300)
    const bool ssa = (t < SMAX);
    const float* ssp = setsizes + ((size_t)base + (size_t)(h*128)) * SMAX + t;
    float ssacc = 0.0f;

    // 4 chunks: {issue 32 ss loads} -> {4 pair columns} -> {consume ss loads}
    #pragma unroll 1
    for (int chunk = 0; chunk < 4; ++chunk) {
        float ssv[32];
        if (ssa) {
            #pragma unroll
            for (int u = 0; u < 32; ++u)
                ssv[u] = ssp[(size_t)(chunk*32 + u) * SMAX];
        }

        float cm[4] = {INFV, INFV, INFV, INFV};
        #pragma unroll
        for (int cc = 0; cc < 4; ++cc) {
            const int j = c0 + chunk*4 + cc;
            const float4 cd0 = *(const float4*)&s_cols[j*8];   // half-wave bcast
            const float4 cd1 = *(const float4*)&s_cols[j*8+4];
            #pragma unroll
            for (int r = 0; r < 4; ++r) {
                float dx=ra[r].x-cd0.x, dy=ra[r].y-cd0.y, dz=ra[r].z-cd0.z;
                float ex=ra[r].w-cd0.w, ey=rb[r].x-cd1.x, ez=rb[r].y-cd1.y;
                float de=rb[r].z-cd1.z;
                float v = s_tab[ccr[r] + j]                    // <=15 rows, bcast
                        + fast_sqrtf(dx*dx + dy*dy + dz*dz)
                        + fast_sqrtf(ex*ex + ey*ey + ez*ez)
                        + de*de;
                rmin[r] = fminf(rmin[r], v);
                cm[cc]  = fminf(cm[cc], v);
            }
        }

        // col-min partial (over this half's 128 rows) -> ws
        #pragma unroll
        for (int cc = 0; cc < 4; ++cc) {
            float v = cm[cc];
            #pragma unroll
            for (int off = 16; off > 0; off >>= 1)
                v = fminf(v, __shfl_down(v, off, 32));
            if (tx == 0) ws[W_COL + blk*NQ + c0 + chunk*4 + cc] = v;
        }

        if (ssa) {
            #pragma unroll
            for (int u = 0; u < 32; ++u) ssacc += ssv[u];
        }
    }

    // ss column partial -> ws
    if (ssa) ws[W_SS + blk*304 + t] = ssacc;

    // row-min partials over ty -> LDS -> complete row mins -> sum
    #pragma unroll
    for (int r = 0; r < 4; ++r)
        s_red[ty*128 + tx + 32*r] = rmin[r];
    __syncthreads();
    if (t < 128) {
        float m = s_red[t];
        #pragma unroll
        for (int k = 1; k < 16; ++k) m = fminf(m, s_red[k*128 + t]);
        #pragma unroll
        for (int off = 32; off > 0; off >>= 1) m += __shfl_down(m, off, 64);
        if ((t & 63) == 0) s_part[t >> 6] = m;
    }
    __syncthreads();
    if (t == 0)
        ws[W_SC + blk] = s_part[0] + s_part[1];
}

// ---------------------------------------------------------------------------
// Combine: per batch, fmin the 2 row-half col-min partials and sum; combine
// ss column partials, softmax+NLL; add row-sum partials -> ws[W_B + b].
// 128 blocks x 512 threads. Plain stores only — no atomics, no init needed.
// ---------------------------------------------------------------------------
__global__ __launch_bounds__(512) void combine_kernel(
    const int* __restrict__ n_particles, float* __restrict__ ws)
{
    __shared__ float s_p[8], s_q[8], s_m[304], s_one[1];
    const int b = blockIdx.x;
    const int t = threadIdx.x;
    const int wave = t >> 6, lane = t & 63;

    // col-min combine + sum
    float v = 0.0f;
    if (t < NQ)
        v = fminf(ws[W_COL + (2*b)*NQ + t], ws[W_COL + (2*b+1)*NQ + t]);
    #pragma unroll
    for (int off = 32; off > 0; off >>= 1) v += __shfl_down(v, off, 64);
    if (lane == 0) s_p[wave] = v;

    // ss combine + softmax
    float m = -INFV;
    if (t < SMAX) {
        m = (ws[W_SS + (2*b)*304 + t] + ws[W_SS + (2*b+1)*304 + t]) * (1.0f / NQ);
        s_m[t] = m;
    }
    float wm = m;
    #pragma unroll
    for (int off = 32; off > 0; off >>= 1) wm = fmaxf(wm, __shfl_down(wm, off, 64));
    if (lane == 0) s_q[wave] = wm;
    __syncthreads();
    if (t == 0) {
        float a = fmaxf(fmaxf(s_q[0], s_q[1]), fmaxf(s_q[2], s_q[3]));
        float c = fmaxf(fmaxf(s_q[4], s_q[5]), fmaxf(s_q[6], s_q[7]));
        s_one[0] = fmaxf(a, c);
    }
    __syncthreads();
    const float mx = s_one[0];
    float e = (t < SMAX) ? __expf(m - mx) : 0.0f;
    #pragma unroll
    for (int off = 32; off > 0; off >>= 1) e += __shfl_down(e, off, 64);
    if (lane == 0) s_q[wave] = e;      // reuse: old s_q consumed above
    __syncthreads();
    if (t == 0) {
        float S = s_q[0]+s_q[1]+s_q[2]+s_q[3]+s_q[4]+s_q[5]+s_q[6]+s_q[7];
        float colsum = s_p[0]+s_p[1]+s_p[2]+s_p[3]+s_p[4]+s_p[5]+s_p[6]+s_p[7];
        int nb = n_particles[b];
        float ssl = -(s_m[nb] - mx - __logf(S));
        ws[W_B + b] = colsum + ws[W_SC + 2*b] + ws[W_SC + 2*b + 1] + ssl;
    }
}

// ---------------------------------------------------------------------------
// Final: sum the 128 batch totals, plain-store out[0]. No memset anywhere.
// ---------------------------------------------------------------------------
__global__ __launch_bounds__(128) void final_kernel(
    const float* __restrict__ ws, float* __restrict__ out, int out_size)
{
    __shared__ float s2[2];
    const int t = threadIdx.x;
    float v = ws[W_B + t];
    #pragma unroll
    for (int off = 32; off > 0; off >>= 1) v += __shfl_down(v, off, 64);
    if ((t & 63) == 0) s2[t >> 6] = v;
    __syncthreads();
    if (t == 0) out[0] = (s2[0] + s2[1]) * (1.0f / BQ);
    for (int i = 1 + t; i < out_size && i < 1024; i += 128) out[i] = 0.0f;
}

extern "C" void kernel_launch(void* const* d_in, const int* in_sizes, int n_in,
                              void* d_out, int out_size, void* d_ws, size_t ws_size,
                              hipStream_t stream) {
    (void)in_sizes; (void)n_in; (void)ws_size;
    const int*   p_class     = (const int*)d_in[0];
    const int*   p_charge    = (const int*)d_in[1];
    const int*   n_particles = (const int*)d_in[2];
    const float* cls_logits  = (const float*)d_in[3];
    const float* chg_logits  = (const float*)d_in[4];
    const float* p_pos       = (const float*)d_in[5];
    const float* pf_pos      = (const float*)d_in[6];
    const float* p_mom       = (const float*)d_in[7];
    const float* pf_mom      = (const float*)d_in[8];
    const float* p_en        = (const float*)d_in[9];
    const float* pf_en       = (const float*)d_in[10];
    const float* setsizes    = (const float*)d_in[11];
    float* out = (float*)d_out;
    float* ws  = (float*)d_ws;   // uses ~574 KB, all written before read

    main_kernel<<<NBLK, 512, 0, stream>>>(
        p_class, p_charge, cls_logits, chg_logits,
        p_pos, pf_pos, p_mom, pf_mom, p_en, pf_en, setsizes, ws);

    combine_kernel<<<BQ, 512, 0, stream>>>(n_particles, ws);

    final_kernel<<<1, 128, 0, stream>>>(ws, out, out_size);
}